// Round 6
// baseline (1805.624 us; speedup 1.0000x reference)
//
#include <hip/hip_runtime.h>

#define NB 32
#define NC 128
#define NH 56
#define NW 56
#define HP 58
#define WP 58
#define KK 1152
#define NPOS 3136                         // 56*56
#define XT_BYTES (NB * HP * WP * NC * 2)  // 27,557,888
#define AW_OFF XT_BYTES

typedef __attribute__((ext_vector_type(8))) short s16x8;
typedef __attribute__((ext_vector_type(16))) float f32x16;
typedef unsigned int u32;

__device__ __forceinline__ unsigned short f2bf(float f) {
    union { float f; unsigned int u; } v; v.f = f;
    unsigned int u = v.u + 0x7fffu + ((v.u >> 16) & 1u);
    return (unsigned short)(u >> 16);
}

__device__ __forceinline__ void gld16(const void* g, void* l) {
    __builtin_amdgcn_global_load_lds(
        (const __attribute__((address_space(1))) u32*)g,
        (__attribute__((address_space(3))) u32*)l, 16, 0, 0);
}

// ---- fused prologue: blocks [0,1792) transpose x; [1792,4096) permute w ----
// xpose: [B,C,56,56]f32 -> x_t [B,58,58,C]bf16 (padded, halo zeroed)
// wconv: w -> A frags for 32x32x16, wave-contiguous:
//   aw[ks 72][wg 2][fi 8][lane 64][j 8]
//   fi = r*2+e; m = r*128+(wg*2+e)*32+(lane&31); k = ks*16+(lane>>5)*8+j
__global__ void k_pro(const float* __restrict__ x, const float* __restrict__ w,
                      unsigned short* __restrict__ xt, unsigned short* __restrict__ aw) {
    int blk = blockIdx.x;
    int tid = threadIdx.x;
    if (blk >= 1792) {
        int idx = (blk - 1792) * 256 + tid;   // 589824 total
        if (idx < 512 * KK) {
            int j = idx & 7, lane = (idx >> 3) & 63;
            int fi = (idx >> 9) & 7, wg = (idx >> 12) & 1, ks = idx >> 13;
            int r = fi >> 1, e = fi & 1;
            int m = r * 128 + (wg * 2 + e) * 32 + (lane & 31);
            int k = ks * 16 + (lane >> 5) * 8 + j;
            int g = k >> 7, ic = k & 127;
            aw[idx] = f2bf(w[(m * 128 + ic) * 9 + g]);
        }
        return;
    }
    __shared__ unsigned short tile[128 * 57];
    int b = blk / NH, y = blk % NH;
    const float* xb = x + (size_t)b * (NC * NPOS) + y * NW;
#pragma unroll
    for (int p = 0; p < 7; ++p) {
        int idx = p * 256 + tid;            // 1792 float4 = 7168 floats
        int c = idx / 14, i = idx - c * 14;
        float4 v = *(const float4*)(xb + c * NPOS + i * 4);
        unsigned short* tp = &tile[c * 57 + i * 4];
        tp[0] = f2bf(v.x); tp[1] = f2bf(v.y); tp[2] = f2bf(v.z); tp[3] = f2bf(v.w);
    }
    __syncthreads();
    unsigned short* xrow = xt + ((size_t)(b * HP + y + 1) * WP + 1) * NC;
#pragma unroll
    for (int p = 0; p < 4; ++p) {
        int idx = p * 256 + tid;            // 896 = 56 x-pos * 16 chunks
        if (idx < 896) {
            int xp = idx >> 4, cgi = idx & 15;
            s16x8 v8;
#pragma unroll
            for (int j = 0; j < 8; ++j)
                v8[j] = (short)tile[(cgi * 8 + j) * 57 + xp];
            *(s16x8*)(xrow + xp * NC + cgi * 8) = v8;
        }
    }
    if (tid < 128) {
        xt[((size_t)(b * HP + y + 1) * WP + 0) * NC + tid] = 0;
        xt[((size_t)(b * HP + y + 1) * WP + 57) * NC + tid] = 0;
    }
    if (y == 0) {
        unsigned short* r0 = xt + (size_t)(b * HP + 0) * WP * NC;
        for (int i = tid; i < WP * NC; i += 256) r0[i] = 0;
    }
    if (y == 55) {
        unsigned short* r57 = xt + (size_t)(b * HP + 57) * WP * NC;
        for (int i = tid; i < WP * NC; i += 256) r57[i] = 0;
    }
}

// ---- main: fused implicit-GEMM conv + softmax rank combine + biases ----
// 32x32x16 MFMA. Block = 256 thr (4 waves), M=512 x N=128 (global-n, spans
// batches), K=1152 = 9 taps x 8 K16-slices. Waves: wg=wv>>1 (m-half: ch 64),
// nh=wv&1 (n-half: 64 pos). Wave = 8 m-tiles (4 ranks x 2 ch32) x 2 n-tiles.
// A: global->VGPR (wave-contiguous frags, L2-resident), 1-slice ping-pong.
// B: LDS 2 x 32KB dbuf, gld16-staged, XOR-16 chunk swizzle (<=2-way reads).
// 2 blocks/CU -> cross-block latency hiding.
__global__ void __launch_bounds__(256, 2) k_main(
    const unsigned short* __restrict__ xt, const unsigned short* __restrict__ aw,
    const float* __restrict__ cwr, const float* __restrict__ cwc,
    const float* __restrict__ brow, const float* __restrict__ bcol,
    const float* __restrict__ bch, float* __restrict__ out) {
    __shared__ __align__(16) unsigned char ldsB[2][32768];   // 128 rows x 256B

    const int tid = threadIdx.x;
    const int lane = tid & 63;
    const int wv = tid >> 6;
    const int wg = wv >> 1, nh = wv & 1;
    const int l31 = lane & 31, hh = lane >> 5;
    const int blk = blockIdx.x;
    const int n0 = blk * 128;

    // ---- B staging: wave stages rows wv*32..+31; 8 gld16 of 4 rows each.
    // lane -> row_local = lane>>4, chunk = lane&15; global chunk = (lane&15)^(row&15)
    const unsigned char* gB[8];
#pragma unroll
    for (int h = 0; h < 8; ++h) {
        int row = wv * 32 + h * 4 + (lane >> 4);
        int ng = n0 + row;
        int b = ng / NPOS, pos = ng - b * NPOS;
        int yy = pos / 56, xx = pos - yy * 56;
        int cg = (lane & 15) ^ (row & 15);
        gB[h] = (const unsigned char*)xt + (size_t)b * (HP * WP * NC * 2)
              + ((yy + 1) * WP + (xx + 1)) * (NC * 2) + cg * 16;
    }

    // ---- A: wave's 8 frags contiguous: 8KB per slice at wg*8192 + ks*16384
    const unsigned char* gA = (const unsigned char*)aw + wg * 8192 + lane * 16;

    s16x8 Areg[2][8];
    f32x16 acc[8][2] = {};    // [fi = r*2+e][t]

    auto aload = [&](int ks, int pp) {
#pragma unroll
        for (int fi = 0; fi < 8; ++fi)
            Areg[pp][fi] = *(const s16x8*)(gA + ks * 16384 + fi * 1024);
    };
    auto bissue = [&](int tap, int buf) {
        int dy = (tap * 11) >> 5, dx = tap - dy * 3;
        int off = ((dy - 1) * WP + (dx - 1)) * (NC * 2);
        unsigned char* L = &ldsB[buf][wv * 8192];
#pragma unroll
        for (int h = 0; h < 8; ++h) gld16(gB[h] + off, L + h * 1024);
    };

    bissue(0, 0);
    aload(0, 0);
    __syncthreads();

    for (int tap = 0; tap < 9; ++tap) {
        const int cur = tap & 1;
        if (tap < 8) bissue(tap + 1, cur ^ 1);
        const unsigned char* L = &ldsB[cur][0];
#pragma unroll
        for (int s8 = 0; s8 < 8; ++s8) {
            int ks = tap * 8 + s8;
            if (ks < 71) aload(ks + 1, (s8 + 1) & 1);
            s16x8 bf[2];
#pragma unroll
            for (int t = 0; t < 2; ++t) {
                int row = (nh * 2 + t) * 32 + l31;
                int pc = (s8 * 2 + hh) ^ (row & 15);
                bf[t] = *(const s16x8*)(L + row * 256 + pc * 16);
            }
#pragma unroll
            for (int fi = 0; fi < 8; ++fi)
#pragma unroll
                for (int t = 0; t < 2; ++t)
                    acc[fi][t] = __builtin_amdgcn_mfma_f32_32x32x16_bf16(
                        Areg[s8 & 1][fi], bf[t], acc[fi][t], 0, 0, 0);
        }
        __syncthreads();
    }

    // ---- epilogue: softmax over rank + combine + biases, fp32 store
    // C/D 32x32: col = lane&31, row = (reg&3) + 8*(reg>>2) + 4*(lane>>5)
#pragma unroll
    for (int t = 0; t < 2; ++t) {
        int ng = n0 + (nh * 2 + t) * 32 + l31;
        int b = ng / NPOS, pos = ng - b * NPOS;
        int yy = pos / 56, xx = pos - yy * 56;
        float v0 = cwr[yy]       + cwc[xx];
        float v1 = cwr[56 + yy]  + cwc[56 + xx];
        float v2 = cwr[112 + yy] + cwc[112 + xx];
        float v3 = cwr[168 + yy] + cwc[168 + xx];
        float mx = fmaxf(fmaxf(v0, v1), fmaxf(v2, v3));
        float e0 = __expf(v0 - mx), e1 = __expf(v1 - mx);
        float e2 = __expf(v2 - mx), e3 = __expf(v3 - mx);
        float inv = 1.0f / (e0 + e1 + e2 + e3);
        float c0 = e0 * inv, c1 = e1 * inv, c2 = e2 * inv, c3 = e3 * inv;
        float rb = brow[yy] + bcol[xx];
        float* ob = out + (size_t)b * NC * NPOS + pos;
#pragma unroll
        for (int e = 0; e < 2; ++e)
#pragma unroll
            for (int reg = 0; reg < 16; ++reg) {
                int ch = (wg * 2 + e) * 32 + (reg & 3) + 8 * (reg >> 2) + 4 * hh;
                float v = acc[0 * 2 + e][t][reg] * c0 + acc[1 * 2 + e][t][reg] * c1
                        + acc[2 * 2 + e][t][reg] * c2 + acc[3 * 2 + e][t][reg] * c3;
                ob[(size_t)ch * NPOS] = v + bch[ch] + rb;
            }
    }
}

extern "C" void kernel_launch(void* const* d_in, const int* in_sizes, int n_in,
                              void* d_out, int out_size, void* d_ws, size_t ws_size,
                              hipStream_t stream) {
    const float* x    = (const float*)d_in[0];
    const float* w    = (const float*)d_in[1];
    const float* cwr  = (const float*)d_in[2];
    const float* cwc  = (const float*)d_in[3];
    const float* brow = (const float*)d_in[4];
    const float* bcol = (const float*)d_in[5];
    const float* bch  = (const float*)d_in[6];
    float* out = (float*)d_out;

    unsigned char* ws = (unsigned char*)d_ws;
    unsigned short* xt = (unsigned short*)ws;
    unsigned short* aw = (unsigned short*)(ws + AW_OFF);

    k_pro<<<4096, 256, 0, stream>>>(x, w, xt, aw);   // xpose + wconv fused
    k_main<<<784, 256, 0, stream>>>(xt, aw, cwr, cwc, brow, bcol, bch, out);
}

// Round 7
// 229.450 us; speedup vs baseline: 7.8694x; 7.8694x over previous
//
#include <hip/hip_runtime.h>

#define NB 32
#define NC 128
#define NH 56
#define NW 56
#define HP 58
#define WP 58
#define KK 1152
#define NPOS 3136                         // 56*56
#define XT_BYTES (NB * HP * WP * NC * 2)  // 27,557,888
#define AW_OFF XT_BYTES

typedef __attribute__((ext_vector_type(8))) short s16x8;
typedef __attribute__((ext_vector_type(4))) float f32x4;
typedef unsigned int u32;

__device__ __forceinline__ unsigned short f2bf(float f) {
    union { float f; unsigned int u; } v; v.f = f;
    unsigned int u = v.u + 0x7fffu + ((v.u >> 16) & 1u);
    return (unsigned short)(u >> 16);
}

__device__ __forceinline__ void gld16(const void* g, void* l) {
    __builtin_amdgcn_global_load_lds(
        (const __attribute__((address_space(1))) u32*)g,
        (__attribute__((address_space(3))) u32*)l, 16, 0, 0);
}

// ---- fused prologue: blocks [0,1792) transpose x; [1792,4096) permute w ----
// xpose: [B,C,56,56]f32 -> x_t [B,58,58,C]bf16 (padded, halo zeroed)
// wconv: w -> A fragments in exact MFMA lane order:
//   aw[s32][mt][lane][j]; m=mt*16+(lane&15); k=s32*32+(lane>>4)*8+j; k=(tap)*128+ic
__global__ void k_pro(const float* __restrict__ x, const float* __restrict__ w,
                      unsigned short* __restrict__ xt, unsigned short* __restrict__ aw) {
    int blk = blockIdx.x;
    int tid = threadIdx.x;
    if (blk >= 1792) {
        int idx = (blk - 1792) * 256 + tid;   // 589824 total
        if (idx < 512 * KK) {
            int j = idx & 7, lane = (idx >> 3) & 63, mt = (idx >> 9) & 31, s = idx >> 14;
            int m = mt * 16 + (lane & 15);
            int kg = s * 32 + (lane >> 4) * 8 + j;
            int g = kg >> 7, ic = kg & 127;
            aw[idx] = f2bf(w[(m * 128 + ic) * 9 + g]);
        }
        return;
    }
    __shared__ unsigned short tile[128 * 57];
    int b = blk / NH, y = blk % NH;
    const float* xb = x + (size_t)b * (NC * NPOS) + y * NW;
#pragma unroll
    for (int p = 0; p < 7; ++p) {
        int idx = p * 256 + tid;            // 1792 float4 = 7168 floats
        int c = idx / 14, i = idx - c * 14;
        float4 v = *(const float4*)(xb + c * NPOS + i * 4);
        unsigned short* tp = &tile[c * 57 + i * 4];
        tp[0] = f2bf(v.x); tp[1] = f2bf(v.y); tp[2] = f2bf(v.z); tp[3] = f2bf(v.w);
    }
    __syncthreads();
    unsigned short* xrow = xt + ((size_t)(b * HP + y + 1) * WP + 1) * NC;
#pragma unroll
    for (int p = 0; p < 4; ++p) {
        int idx = p * 256 + tid;            // 896 = 56 x-pos * 16 chunks
        if (idx < 896) {
            int xp = idx >> 4, cgi = idx & 15;
            s16x8 v8;
#pragma unroll
            for (int j = 0; j < 8; ++j)
                v8[j] = (short)tile[(cgi * 8 + j) * 57 + xp];
            *(s16x8*)(xrow + xp * NC + cgi * 8) = v8;
        }
    }
    if (tid < 128) {
        xt[((size_t)(b * HP + y + 1) * WP + 0) * NC + tid] = 0;
        xt[((size_t)(b * HP + y + 1) * WP + 57) * NC + tid] = 0;
    }
    if (y == 0) {
        unsigned short* r0 = xt + (size_t)(b * HP + 0) * WP * NC;
        for (int i = tid; i < WP * NC; i += 256) r0[i] = 0;
    }
    if (y == 55) {
        unsigned short* r57 = xt + (size_t)(b * HP + 57) * WP * NC;
        for (int i = tid; i < WP * NC; i += 256) r57[i] = 0;
    }
}

// ---- main: fused implicit-GEMM conv + softmax rank combine + biases ----
// 8 waves, M=512 (4 ranks x 128 ch), N=112 (2 image rows), K=1152.
// 9 barrier-stages of K=128 = one 3x3 filter tap each. A: global->VGPR
// ping-pong. B: shared LDS 2x28KB dbuf via gld16, XOR-16 chunk swizzle.
// PHASE STAGGER: odd waves process the 4 K32 sub-slices rotated by 2, so the
// two waves on each SIMD anti-align their ds_read bursts vs MFMA bursts.
__global__ void __launch_bounds__(512, 2) k_main(
    const unsigned short* __restrict__ xt, const unsigned short* __restrict__ aw,
    const float* __restrict__ cwr, const float* __restrict__ cwc,
    const float* __restrict__ brow, const float* __restrict__ bcol,
    const float* __restrict__ bch, float* __restrict__ out) {
    __shared__ __align__(16) unsigned char ldsB[2][28672];   // 112 rows x 256B

    const int tid = threadIdx.x;
    const int lane = tid & 63;
    const int wv = tid >> 6;
    const int l15 = lane & 15, quad = lane >> 4;
    const int ph = (wv & 1) * 2;            // per-parity sub-slice rotation
    const int blk = blockIdx.x;
    const int b = blk / 28;
    const int tile0 = (blk - b * 28) * 112;

    const unsigned char* xt_b = (const unsigned char*)xt + (size_t)b * (HP * WP * NC * 2);
    const unsigned char* gA = (const unsigned char*)aw + wv * 1024 + lane * 16;

    // B staging: wave wv (0..6) stages rows wv*16..+15; gld16 #h covers 4 rows
    // (h*4 + lane>>4), phys chunk lane&15, global chunk (lane&15)^(row&15).
    const unsigned char* gB[4];
    if (wv < 7) {
#pragma unroll
        for (int h = 0; h < 4; ++h) {
            int rl = h * 4 + (lane >> 4);
            int row = wv * 16 + rl;
            int pos = tile0 + row;
            int yy = pos / 56, xx = pos - yy * 56;
            int c = (lane & 15) ^ rl;
            gB[h] = xt_b + ((yy + 1) * WP + (xx + 1)) * (NC * 2) + c * 16;
        }
    }

    s16x8 Areg[2][4];          // [pingpong][rank]
    f32x4 acc[4][7] = {};      // [rank][ntile]

    auto aload = [&](int s32, int pp) {
#pragma unroll
        for (int r = 0; r < 4; ++r)
            Areg[pp][r] = *(const s16x8*)(gA + s32 * 32768 + r * 8192);
    };
    auto bissue = [&](int st, int buf) {
        if (wv < 7) {
            int dy = (st * 11) >> 5, dx = st - dy * 3;
            int off = ((dy - 1) * WP + (dx - 1)) * (NC * 2);
            unsigned char* L = &ldsB[buf][wv * 4096];
#pragma unroll
            for (int h = 0; h < 4; ++h) gld16(gB[h] + off, L + h * 1024);
        }
    };

    aload(ph, 0);              // first slice in this wave's rotated sequence
    bissue(0, 0);
    __syncthreads();

    for (int st = 0; st < 9; ++st) {
        const int cur = st & 1;
        if (st < 8) bissue(st + 1, cur ^ 1);
        const unsigned char* L = &ldsB[cur][0];
#pragma unroll
        for (int j = 0; j < 4; ++j) {
            const int kkw = (j + ph) & 3;      // this wave's sub-slice this beat
            // prefetch next slice in this wave's own sequence
            if (!(st == 8 && j == 3)) {
                int nslice = (j < 3) ? st * 4 + (((j + 1) + ph) & 3)
                                     : (st + 1) * 4 + ph;
                aload(nslice, (j + 1) & 1);
            }
            s16x8 bf[7];
#pragma unroll
            for (int t = 0; t < 7; ++t)
                bf[t] = *(const s16x8*)(L + (t * 16 + l15) * 256
                                          + (((kkw * 4 + quad) ^ l15) << 4));
#pragma unroll
            for (int r = 0; r < 4; ++r)
#pragma unroll
                for (int t = 0; t < 7; ++t)
                    acc[r][t] = __builtin_amdgcn_mfma_f32_16x16x32_bf16(
                        Areg[j & 1][r], bf[t], acc[r][t], 0, 0, 0);
        }
        __syncthreads();
    }

    // epilogue: inline softmax over rank + combine + biases, fp32 store
#pragma unroll
    for (int t = 0; t < 7; ++t) {
        int pos = tile0 + t * 16 + l15;
        int yy = pos / 56, xx = pos - yy * 56;
        float v0 = cwr[yy]       + cwc[xx];
        float v1 = cwr[56 + yy]  + cwc[56 + xx];
        float v2 = cwr[112 + yy] + cwc[112 + xx];
        float v3 = cwr[168 + yy] + cwc[168 + xx];
        float mx = fmaxf(fmaxf(v0, v1), fmaxf(v2, v3));
        float e0 = __expf(v0 - mx), e1 = __expf(v1 - mx);
        float e2 = __expf(v2 - mx), e3 = __expf(v3 - mx);
        float inv = 1.0f / (e0 + e1 + e2 + e3);
        float c0 = e0 * inv, c1 = e1 * inv, c2 = e2 * inv, c3 = e3 * inv;
        float rb = brow[yy] + bcol[xx];
#pragma unroll
        for (int r = 0; r < 4; ++r) {
            int ch = wv * 16 + quad * 4 + r;
            float v = acc[0][t][r] * c0 + acc[1][t][r] * c1
                    + acc[2][t][r] * c2 + acc[3][t][r] * c3;
            out[((size_t)b * NC + ch) * NPOS + pos] = v + bch[ch] + rb;
        }
    }
}

extern "C" void kernel_launch(void* const* d_in, const int* in_sizes, int n_in,
                              void* d_out, int out_size, void* d_ws, size_t ws_size,
                              hipStream_t stream) {
    const float* x    = (const float*)d_in[0];
    const float* w    = (const float*)d_in[1];
    const float* cwr  = (const float*)d_in[2];
    const float* cwc  = (const float*)d_in[3];
    const float* brow = (const float*)d_in[4];
    const float* bcol = (const float*)d_in[5];
    const float* bch  = (const float*)d_in[6];
    float* out = (float*)d_out;

    unsigned char* ws = (unsigned char*)d_ws;
    unsigned short* xt = (unsigned short*)ws;
    unsigned short* aw = (unsigned short*)(ws + AW_OFF);

    k_pro<<<4096, 256, 0, stream>>>(x, w, xt, aw);   // xpose + wconv fused
    k_main<<<NB * 28, 512, 0, stream>>>(xt, aw, cwr, cwc, brow, bcol, bch, out);
}